// Round 3
// baseline (464.450 us; speedup 1.0000x reference)
//
#include <hip/hip_runtime.h>

// TropicalMultiHeadAttention — MI355X (gfx950)  Round 3
// B=2, L=1024, D=1024, H=16, dk=64, SCALE=0.125; causal (mask input ignored).
// Outputs: out (2,1024,1024) f32 ++ attn (2,16,1024,1024) f32.
//
// R3 = isolation round after R2's absmax 0.338:
//  * KEEP: packed-f16 scores inner loop (pk_add/pk_max + v_dot2_f32_f16), f16 qkv buffer
//  * REVERT: gemm -> classic VGPR staging w/ padded LDS rows (R1-proven pattern, scaled to 128x128)
//  * REVERT: pv -> R1's verified f32 VALU kernel (V cvt f16->f32 during staging); no vtrans
// If this passes, R2's bug was in global_load_lds staging or pv-MFMA/vtrans.
// If it fails, the packed scores loop is the bug.

typedef _Float16 f16;
typedef __attribute__((ext_vector_type(2))) _Float16 h2;
typedef __attribute__((ext_vector_type(8))) _Float16 f16x8;
typedef __attribute__((ext_vector_type(4))) float f32x4;

__device__ inline f32x4 mfma_f16(f16x8 a, f16x8 b, f32x4 c) {
    return __builtin_amdgcn_mfma_f32_16x16x32_f16(a, b, c, 0, 0, 0);
}

__device__ inline float dot2acc(h2 a, h2 b, float c) {
#if __has_builtin(__builtin_amdgcn_fdot2)
    return __builtin_amdgcn_fdot2(a, b, c, false);
#else
    c = fmaf((float)a[0], (float)b[0], c);
    return fmaf((float)a[1], (float)b[1], c);
#endif
}

// ---------------------------------------------------------------- cvt f32->f16
__global__ __launch_bounds__(256) void cvt_kernel(const float* __restrict__ s,
                                                  f16* __restrict__ d, int n4) {
    int i = blockIdx.x * 256 + threadIdx.x;
    if (i < n4) {
        float4 v = *(const float4*)(s + (size_t)i * 4);
        f16 o[4] = {(f16)v.x, (f16)v.y, (f16)v.z, (f16)v.w};
        *(uint2*)(d + (size_t)i * 4) = *(uint2*)o;
    }
}

// ---------------------------------------------------------------- gate GEMV (f32, R1-proven)
__global__ __launch_bounds__(256) void gate_kernel(const float* __restrict__ x,
                                                   const float* __restrict__ Wg,
                                                   const float* __restrict__ bg,
                                                   float* __restrict__ gbuf) {
    int tg = blockIdx.x * 256 + threadIdx.x;  // (b*1024+l)*16 + h
    int h = tg & 15, row = tg >> 4;
    const float* xp = x + (size_t)row * 1024;
    const float* wp = Wg + (size_t)h * 1024;
    float acc = bg[h];
    for (int k = 0; k < 1024; k += 4) {
        float4 xv = *(const float4*)(xp + k);
        float4 wv = *(const float4*)(wp + k);
        acc = fmaf(xv.x, wv.x, acc);
        acc = fmaf(xv.y, wv.y, acc);
        acc = fmaf(xv.z, wv.z, acc);
        acc = fmaf(xv.w, wv.w, acc);
    }
    gbuf[tg] = 1.0f / (1.0f + __expf(-acc));
}

// ---------------------------------------------------------------- 128x128 MFMA GEMM  C = A @ B^T + bias
// Classic VGPR staging (R1-proven pattern scaled 2x2), padded LDS rows (+8), BK=32, 4 waves.
template <bool OUT16>
__global__ __launch_bounds__(256) void gemm128(const f16* __restrict__ A,
                                               const f16* __restrict__ B,
                                               void* __restrict__ Cv,
                                               const float* __restrict__ b0,
                                               const float* __restrict__ b1,
                                               const float* __restrict__ b2,
                                               int K, int lda, int ldb, int ldc) {
    __shared__ f16 At[128][40];   // 80B row stride, 16B-aligned
    __shared__ f16 Bt[128][40];
    const int t = threadIdx.x;
    const int m0 = blockIdx.y * 128, n0 = blockIdx.x * 128;
    const int wave = t >> 6, lane = t & 63;
    const int l16 = lane & 15, quad = lane >> 4;
    const int wm = (wave >> 1) * 64, wn = (wave & 1) * 64;
    const int sr = t >> 1, sc = (t & 1) * 16;   // staging: 128 rows x 32 k, 16 f16/thread
    f32x4 acc[4][4] = {};
    for (int k0 = 0; k0 < K; k0 += 32) {
        __syncthreads();
        const f16* Ap = A + (size_t)(m0 + sr) * lda + k0 + sc;
        const f16* Bp = B + (size_t)(n0 + sr) * ldb + k0 + sc;
        *(uint4*)&At[sr][sc]     = *(const uint4*)Ap;
        *(uint4*)&At[sr][sc + 8] = *(const uint4*)(Ap + 8);
        *(uint4*)&Bt[sr][sc]     = *(const uint4*)Bp;
        *(uint4*)&Bt[sr][sc + 8] = *(const uint4*)(Bp + 8);
        __syncthreads();
        f16x8 af[4], bfr[4];
#pragma unroll
        for (int i = 0; i < 4; ++i) {
            af[i]  = *(const f16x8*)&At[wm + i * 16 + l16][quad * 8];
            bfr[i] = *(const f16x8*)&Bt[wn + i * 16 + l16][quad * 8];
        }
#pragma unroll
        for (int mi = 0; mi < 4; ++mi)
#pragma unroll
            for (int ni = 0; ni < 4; ++ni)
                acc[mi][ni] = mfma_f16(af[mi], bfr[ni], acc[mi][ni]);
    }
#pragma unroll
    for (int mi = 0; mi < 4; ++mi) {
#pragma unroll
        for (int ni = 0; ni < 4; ++ni) {
            int gcol = n0 + wn + ni * 16 + l16;
            const float* bp = (gcol < 1024) ? b0 : (gcol < 2048 ? b1 : b2);
            float bias = bp[gcol & 1023];
#pragma unroll
            for (int rg = 0; rg < 4; ++rg) {
                int grow = m0 + wm + mi * 16 + quad * 4 + rg;
                float v = acc[mi][ni][rg] + bias;
                if (OUT16)
                    ((f16*)Cv)[(size_t)grow * ldc + gcol] = (f16)v;
                else
                    ((float*)Cv)[(size_t)grow * ldc + gcol] = v;
            }
        }
    }
}

// ---------------------------------------------------------------- scores + softmax + attn write
// Block: (b,h,16-row q-tile). Packed-f16 tropical + fdot2 classical from f16 qkv.
__global__ __launch_bounds__(256) void scores_kernel(const f16* __restrict__ qkv16,
                                                     const float* __restrict__ gbuf,
                                                     const float* __restrict__ log_temps,
                                                     float* __restrict__ attn) {
    __shared__ f16 Qs[16][64];
    __shared__ f16 Ssm[16][1024];
    __shared__ float gsm[16];
    const int t = threadIdx.x;
    const int qt = 63 - (blockIdx.x >> 5);  // heavy tiles first
    const int bh = blockIdx.x & 31;
    const int b = bh & 1, h = bh >> 1;
    const int q0 = qt << 4;
    {
        int rr = t >> 4, cc = (t & 15) * 4;
        *(uint2*)&Qs[rr][cc] =
            *(const uint2*)(qkv16 + (size_t)(b * 1024 + q0 + rr) * 3072 + h * 64 + cc);
    }
    if (t < 16) gsm[t] = gbuf[(size_t)(b * 1024 + q0 + t) * 16 + h];
    float tau = __expf(log_temps[h]);
    tau = fminf(fmaxf(tau, 0.02f), 10.0f);
    const float invtau = 1.0f / tau;
    __syncthreads();

    const int qmax = q0 + 15;
    const int nkt = (qmax >> 8) + 1;
    for (int kt = 0; kt < nkt; ++kt) {
        int k = (kt << 8) + t;
        if (k <= qmax) {
            const f16* Kp = qkv16 + (size_t)(b * 1024 + k) * 3072 + 1024 + h * 64;
            h2 kr[32];
#pragma unroll
            for (int i = 0; i < 8; ++i) *(f16x8*)&kr[i * 4] = ((const f16x8*)Kp)[i];
#pragma unroll 4
            for (int q = 0; q < 16; ++q) {
                h2 qr[32];
#pragma unroll
                for (int i = 0; i < 8; ++i) *(f16x8*)&qr[i * 4] = *(const f16x8*)&Qs[q][i * 8];
                float dot = 0.f;
                h2 tm2 = {(f16)-65504.f, (f16)-65504.f};
#pragma unroll
                for (int i = 0; i < 32; ++i) {
                    h2 qa = qr[i];
                    h2 s2 = qa + kr[i];                        // v_pk_add_f16
                    tm2 = __builtin_elementwise_max(tm2, s2);  // v_pk_max_f16
                    dot = dot2acc(qa, kr[i], dot);             // v_dot2_f32_f16
                }
                float tm = fmaxf((float)tm2[0], (float)tm2[1]);
                float g = gsm[q];
                Ssm[q][k] = (f16)((g * tm + (1.0f - g) * dot) * 0.125f);
            }
        }
    }
    __syncthreads();

    const int lane = t & 63, w = t >> 6;
#pragma unroll
    for (int j = 0; j < 4; ++j) {
        int q = w * 4 + j;
        int qg = q0 + q;
        float m = -1e30f;
        for (int k = lane; k <= qg; k += 64) m = fmaxf(m, (float)Ssm[q][k]);
#pragma unroll
        for (int o = 32; o > 0; o >>= 1) m = fmaxf(m, __shfl_xor(m, o));
        float ssum = 0.f;
        for (int k = lane; k <= qg; k += 64) {
            float e = __expf(((float)Ssm[q][k] - m) * invtau);
            Ssm[q][k] = (f16)e;
            ssum += e;
        }
#pragma unroll
        for (int o = 32; o > 0; o >>= 1) ssum += __shfl_xor(ssum, o);
        float inv = 1.0f / ssum;
        float* orow = attn + ((size_t)((b * 16 + h) * 1024 + qg) << 10);
        for (int k = lane; k < 1024; k += 64)
            orow[k] = (k <= qg) ? (float)Ssm[q][k] * inv : 0.0f;
    }
}

// ---------------------------------------------------------------- PV: out_heads = attn @ V
// R1-verified f32 VALU kernel; V staged f16->f32 into LDS. attn above diag is exact 0.
__global__ __launch_bounds__(256) void pv_kernel(const float* __restrict__ attn,
                                                 const f16* __restrict__ qkv16,
                                                 f16* __restrict__ oh) {
    __shared__ float Vt[64][64];
    const int t = threadIdx.x;
    const int qt = 7 - (blockIdx.x >> 5);
    const int bh = blockIdx.x & 31;
    const int b = bh & 1, h = bh >> 1;
    const int q0 = qt << 7;
    const int qgrp = t >> 3, dgrp = t & 7;
    const int d0 = dgrp << 3;
    const int qb = q0 + (qgrp << 2);  // rows qb..qb+3, cols d0..d0+7
    float acc[4][8] = {};
    const int nkt = (q0 >> 6) + 2;  // k covers [0, q0+128)
    const int vr = t >> 2, vc = (t & 3) << 4;
    const float* attn_bh = attn + ((size_t)(b * 16 + h) << 20);
    for (int kt = 0; kt < nkt; ++kt) {
        int kbase = kt << 6;
        __syncthreads();
        {
            const f16* Vp = qkv16 + (size_t)(b * 1024 + kbase + vr) * 3072 + 2048 + h * 64 + vc;
#pragma unroll
            for (int i = 0; i < 2; ++i) {
                f16x8 v8 = *(const f16x8*)(Vp + i * 8);
#pragma unroll
                for (int j = 0; j < 8; ++j) Vt[vr][vc + i * 8 + j] = (float)v8[j];
            }
        }
        __syncthreads();
        for (int k4 = 0; k4 < 64; k4 += 4) {
            float4 p[4];
#pragma unroll
            for (int j = 0; j < 4; ++j)
                p[j] = *(const float4*)(attn_bh + (size_t)(qb + j) * 1024 + kbase + k4);
#pragma unroll
            for (int kk = 0; kk < 4; ++kk) {
                float4 va = *(const float4*)&Vt[k4 + kk][d0];
                float4 vb = *(const float4*)&Vt[k4 + kk][d0 + 4];
#pragma unroll
                for (int j = 0; j < 4; ++j) {
                    float pj = (kk == 0) ? p[j].x : (kk == 1) ? p[j].y : (kk == 2) ? p[j].z : p[j].w;
                    acc[j][0] = fmaf(pj, va.x, acc[j][0]);
                    acc[j][1] = fmaf(pj, va.y, acc[j][1]);
                    acc[j][2] = fmaf(pj, va.z, acc[j][2]);
                    acc[j][3] = fmaf(pj, va.w, acc[j][3]);
                    acc[j][4] = fmaf(pj, vb.x, acc[j][4]);
                    acc[j][5] = fmaf(pj, vb.y, acc[j][5]);
                    acc[j][6] = fmaf(pj, vb.z, acc[j][6]);
                    acc[j][7] = fmaf(pj, vb.w, acc[j][7]);
                }
            }
        }
    }
#pragma unroll
    for (int j = 0; j < 4; ++j) {
        f16 o[8];
#pragma unroll
        for (int i = 0; i < 8; ++i) o[i] = (f16)acc[j][i];
        *(uint4*)(oh + (size_t)(b * 1024 + qb + j) * 1024 + h * 64 + d0) = *(uint4*)o;
    }
}

// ----------------------------------------------------------------
extern "C" void kernel_launch(void* const* d_in, const int* in_sizes, int n_in,
                              void* d_out, int out_size, void* d_ws, size_t ws_size,
                              hipStream_t stream) {
    const float* x  = (const float*)d_in[0];
    // d_in[1] = mask (causal by construction; unused)
    const float* Wq = (const float*)d_in[2];
    const float* bq = (const float*)d_in[3];
    const float* Wk = (const float*)d_in[4];
    const float* bk = (const float*)d_in[5];
    const float* Wv = (const float*)d_in[6];
    const float* bv = (const float*)d_in[7];
    const float* Wo = (const float*)d_in[8];
    const float* bo = (const float*)d_in[9];
    const float* Wg = (const float*)d_in[10];
    const float* bg = (const float*)d_in[11];
    const float* lt = (const float*)d_in[12];
    float* out = (float*)d_out;
    float* attn = out + (size_t)2 * 1024 * 1024;

    char* ws = (char*)d_ws;
    const size_t MB = (size_t)1 << 20;
    f16*   x16   = (f16*)ws;                  // 4 MiB (2048x1024)
    f16*   w16   = (f16*)(ws + 4 * MB);       // 6 MiB (3072x1024, Wq|Wk|Wv)
    f16*   wo16  = (f16*)(ws + 10 * MB);      // 2 MiB
    f16*   qkv16 = (f16*)(ws + 12 * MB);      // 12 MiB (2048x3072)
    float* gbuf  = (float*)(ws + 24 * MB);    // 128 KiB
    f16*   oh16  = (f16*)(ws + 25 * MB);      // 4 MiB — total 29 MiB

    cvt_kernel<<<2048, 256, 0, stream>>>(x, x16, 524288);
    cvt_kernel<<<1024, 256, 0, stream>>>(Wq, w16, 262144);
    cvt_kernel<<<1024, 256, 0, stream>>>(Wk, w16 + (1 << 20), 262144);
    cvt_kernel<<<1024, 256, 0, stream>>>(Wv, w16 + (2 << 20), 262144);
    cvt_kernel<<<1024, 256, 0, stream>>>(Wo, wo16, 262144);
    gate_kernel<<<128, 256, 0, stream>>>(x, Wg, bg, gbuf);
    gemm128<true><<<dim3(24, 16), 256, 0, stream>>>(x16, w16, qkv16, bq, bk, bv,
                                                    1024, 1024, 1024, 3072);
    scores_kernel<<<2048, 256, 0, stream>>>(qkv16, gbuf, lt, attn);
    pv_kernel<<<256, 256, 0, stream>>>(attn, qkv16, oh16);
    gemm128<false><<<dim3(8, 16), 256, 0, stream>>>(oh16, wo16, out, bo, bo, bo,
                                                    1024, 1024, 1024, 1024);
}

// Round 6
// 340.699 us; speedup vs baseline: 1.3632x; 1.3632x over previous
//
#include <hip/hip_runtime.h>

// TropicalMultiHeadAttention — MI355X (gfx950)  Round 6 (= R5 resubmitted; R5 hit an
// infra failure "container failed twice", no bench data).
// B=2, L=1024, D=1024, H=16, dk=64, SCALE=0.125; causal (mask input ignored).
// Outputs: out (2,1024,1024) f32 ++ attn (2,16,1024,1024) f32.
//
// vs R4: THE BUG — pv read attn at offset (bh<<20) where bh=(h<<1)|b, but attn
// layout needs (b*16+h)<<20: wrong head's P paired with right head's V (absmax 0.338,
// bit-identical in R2 & R4). Fixed. Async global_load_lds gemm reintroduced (exonerated
// by identical-absmax evidence), ported to 128x64 tile (qkv grid 768 = 3 blocks/CU).

typedef _Float16 f16;
typedef __attribute__((ext_vector_type(2))) _Float16 h2;
typedef __attribute__((ext_vector_type(8))) _Float16 f16x8;
typedef __attribute__((ext_vector_type(4))) float f32x4;

__device__ inline f32x4 mfma_f16(f16x8 a, f16x8 b, f32x4 c) {
    return __builtin_amdgcn_mfma_f32_16x16x32_f16(a, b, c, 0, 0, 0);
}

__device__ inline void async_copy16(const f16* g, f16* l) {
    __builtin_amdgcn_global_load_lds((const __attribute__((address_space(1))) void*)g,
                                     (__attribute__((address_space(3))) void*)l, 16, 0, 0);
}

__device__ inline float dot2acc(h2 a, h2 b, float c) {
#if __has_builtin(__builtin_amdgcn_fdot2)
    return __builtin_amdgcn_fdot2(a, b, c, false);
#else
    c = fmaf((float)a[0], (float)b[0], c);
    return fmaf((float)a[1], (float)b[1], c);
#endif
}

// ---------------------------------------------------------------- cvt f32->f16
__global__ __launch_bounds__(256) void cvt_kernel(const float* __restrict__ s,
                                                  f16* __restrict__ d, int n4) {
    int i = blockIdx.x * 256 + threadIdx.x;
    if (i < n4) {
        float4 v = *(const float4*)(s + (size_t)i * 4);
        f16 o[4] = {(f16)v.x, (f16)v.y, (f16)v.z, (f16)v.w};
        *(uint2*)(d + (size_t)i * 4) = *(uint2*)o;
    }
}

// ---------------------------------------------------------------- gate: block = one row, 16 lanes/head
__global__ __launch_bounds__(256) void gate_kernel(const float* __restrict__ x,
                                                   const float* __restrict__ Wg,
                                                   const float* __restrict__ bg,
                                                   float* __restrict__ gbuf) {
    const int row = blockIdx.x;          // 0..2047 = b*1024+l
    const int t = threadIdx.x;
    const int h = t >> 4, li = t & 15;
    const float* xp = x + (size_t)row * 1024;
    const float* wp = Wg + (size_t)h * 1024;
    float acc = 0.f;
#pragma unroll
    for (int j = 0; j < 16; ++j) {
        int d = li * 4 + j * 64;
        float4 xv = *(const float4*)(xp + d);
        float4 wv = *(const float4*)(wp + d);
        acc = fmaf(xv.x, wv.x, acc);
        acc = fmaf(xv.y, wv.y, acc);
        acc = fmaf(xv.z, wv.z, acc);
        acc = fmaf(xv.w, wv.w, acc);
    }
#pragma unroll
    for (int o = 8; o > 0; o >>= 1) acc += __shfl_xor(acc, o);
    if (li == 0) gbuf[(size_t)row * 16 + h] = 1.0f / (1.0f + __expf(-(acc + bg[h])));
}

// ---------------------------------------------------------------- 128x64 MFMA GEMM  C = A @ B^T + bias
// Async global_load_lds staging, BK=32, 4 waves in 2x2 of (64m x 32n).
// LDS linear [row*32+col] f16; async dest = lane's &buf[t*8] (wave-uniform base + lane*16B).
template <bool OUT16>
__global__ __launch_bounds__(256) void gemm128(const f16* __restrict__ A,
                                               const f16* __restrict__ B,
                                               void* __restrict__ Cv,
                                               const float* __restrict__ b0,
                                               const float* __restrict__ b1,
                                               const float* __restrict__ b2,
                                               int K, int lda, int ldb, int ldc) {
    __shared__ f16 At[128 * 32];
    __shared__ f16 Bt[64 * 32];
    const int t = threadIdx.x;
    const int m0 = blockIdx.y * 128, n0 = blockIdx.x * 64;
    const int wave = t >> 6, lane = t & 63;
    const int l16 = lane & 15, quad = lane >> 4;
    const int wm = (wave >> 1) * 64, wn = (wave & 1) * 32;
    const int sr = t >> 2, sc = (t & 3) * 8;  // LDS offset t*8 f16 <-> row t/4, col (t%4)*8
    f32x4 acc[4][2] = {};
    for (int k0 = 0; k0 < K; k0 += 32) {
        __syncthreads();
#pragma unroll
        for (int i = 0; i < 2; ++i)
            async_copy16(A + (size_t)(m0 + sr + i * 64) * lda + k0 + sc, &At[t * 8 + i * 2048]);
        async_copy16(B + (size_t)(n0 + sr) * ldb + k0 + sc, &Bt[t * 8]);
        __syncthreads();
        f16x8 af[4], bfr[2];
#pragma unroll
        for (int i = 0; i < 4; ++i)
            af[i] = *(const f16x8*)&At[(wm + i * 16 + l16) * 32 + quad * 8];
#pragma unroll
        for (int i = 0; i < 2; ++i)
            bfr[i] = *(const f16x8*)&Bt[(wn + i * 16 + l16) * 32 + quad * 8];
#pragma unroll
        for (int mi = 0; mi < 4; ++mi)
#pragma unroll
            for (int ni = 0; ni < 2; ++ni)
                acc[mi][ni] = mfma_f16(af[mi], bfr[ni], acc[mi][ni]);
    }
#pragma unroll
    for (int mi = 0; mi < 4; ++mi) {
#pragma unroll
        for (int ni = 0; ni < 2; ++ni) {
            int gcol = n0 + wn + ni * 16 + l16;
            const float* bp = (gcol < 1024) ? b0 : (gcol < 2048 ? b1 : b2);
            float bias = bp[gcol & 1023];
#pragma unroll
            for (int rg = 0; rg < 4; ++rg) {
                int grow = m0 + wm + mi * 16 + quad * 4 + rg;
                float v = acc[mi][ni][rg] + bias;
                if (OUT16)
                    ((f16*)Cv)[(size_t)grow * ldc + gcol] = (f16)v;
                else
                    ((float*)Cv)[(size_t)grow * ldc + gcol] = v;
            }
        }
    }
}

// ---------------------------------------------------------------- V transpose: vt16[(bh)*64+d][k] = V[k][d]
__global__ __launch_bounds__(256) void vtrans_kernel(const f16* __restrict__ qkv16,
                                                     f16* __restrict__ vt16) {
    __shared__ f16 T[64][72];
    const int t = threadIdx.x;
    const int kt = blockIdx.x >> 5, bh = blockIdx.x & 31;
    const int b = bh & 1, h = bh >> 1;
    {
        int k = t >> 2, d0 = (t & 3) * 16;
        const f16* src = qkv16 + (size_t)(b * 1024 + kt * 64 + k) * 3072 + 2048 + h * 64 + d0;
        *(uint4*)&T[k][d0] = *(const uint4*)src;
        *(uint4*)&T[k][d0 + 8] = *(const uint4*)(src + 8);
    }
    __syncthreads();
    {
        int d = t >> 2, k4 = (t & 3) * 16;
        f16 o[16];
#pragma unroll
        for (int j = 0; j < 16; ++j) o[j] = T[k4 + j][d];
        f16* dst = vt16 + (size_t)(bh * 64 + d) * 1024 + kt * 64 + k4;
        *(uint4*)dst = *(uint4*)&o[0];
        *(uint4*)(dst + 8) = *(uint4*)&o[8];
    }
}

// ---------------------------------------------------------------- scores + softmax + attn write (R3-proven)
__global__ __launch_bounds__(256) void scores_kernel(const f16* __restrict__ qkv16,
                                                     const float* __restrict__ gbuf,
                                                     const float* __restrict__ log_temps,
                                                     float* __restrict__ attn) {
    __shared__ f16 Qs[16][64];
    __shared__ f16 Ssm[16][1024];
    __shared__ float gsm[16];
    const int t = threadIdx.x;
    const int qt = 63 - (blockIdx.x >> 5);  // heavy tiles first
    const int bh = blockIdx.x & 31;
    const int b = bh & 1, h = bh >> 1;
    const int q0 = qt << 4;
    {
        int rr = t >> 4, cc = (t & 15) * 4;
        *(uint2*)&Qs[rr][cc] =
            *(const uint2*)(qkv16 + (size_t)(b * 1024 + q0 + rr) * 3072 + h * 64 + cc);
    }
    if (t < 16) gsm[t] = gbuf[(size_t)(b * 1024 + q0 + t) * 16 + h];
    float tau = __expf(log_temps[h]);
    tau = fminf(fmaxf(tau, 0.02f), 10.0f);
    const float invtau = 1.0f / tau;
    __syncthreads();

    const int qmax = q0 + 15;
    const int nkt = (qmax >> 8) + 1;
    for (int kt = 0; kt < nkt; ++kt) {
        int k = (kt << 8) + t;
        if (k <= qmax) {
            const f16* Kp = qkv16 + (size_t)(b * 1024 + k) * 3072 + 1024 + h * 64;
            h2 kr[32];
#pragma unroll
            for (int i = 0; i < 8; ++i) *(f16x8*)&kr[i * 4] = ((const f16x8*)Kp)[i];
#pragma unroll 4
            for (int q = 0; q < 16; ++q) {
                h2 qr[32];
#pragma unroll
                for (int i = 0; i < 8; ++i) *(f16x8*)&qr[i * 4] = *(const f16x8*)&Qs[q][i * 8];
                float dot = 0.f;
                h2 tm2 = {(f16)-65504.f, (f16)-65504.f};
#pragma unroll
                for (int i = 0; i < 32; ++i) {
                    h2 qa = qr[i];
                    h2 s2 = qa + kr[i];
                    tm2 = __builtin_elementwise_max(tm2, s2);
                    dot = dot2acc(qa, kr[i], dot);
                }
                float tm = fmaxf((float)tm2[0], (float)tm2[1]);
                float g = gsm[q];
                Ssm[q][k] = (f16)((g * tm + (1.0f - g) * dot) * 0.125f);
            }
        }
    }
    __syncthreads();

    const int lane = t & 63, w = t >> 6;
#pragma unroll
    for (int j = 0; j < 4; ++j) {
        int q = w * 4 + j;
        int qg = q0 + q;
        float m = -1e30f;
        for (int k = lane; k <= qg; k += 64) m = fmaxf(m, (float)Ssm[q][k]);
#pragma unroll
        for (int o = 32; o > 0; o >>= 1) m = fmaxf(m, __shfl_xor(m, o));
        float ssum = 0.f;
        for (int k = lane; k <= qg; k += 64) {
            float e = __expf(((float)Ssm[q][k] - m) * invtau);
            Ssm[q][k] = (f16)e;
            ssum += e;
        }
#pragma unroll
        for (int o = 32; o > 0; o >>= 1) ssum += __shfl_xor(ssum, o);
        float inv = 1.0f / ssum;
        float* orow = attn + ((size_t)((b * 16 + h) * 1024 + qg) << 10);
        for (int k = lane; k < 1024; k += 64)
            orow[k] = (k <= qg) ? (float)Ssm[q][k] * inv : 0.0f;
    }
}

// ---------------------------------------------------------------- PV via MFMA f16
// Block: (b,h,128-row q-tile). P staged from attn f32 (cvt in regs); V from vt16.
// attn layout index is (b*16+h) — NOT the bh=(h<<1)|b block encoding (R2/R4 bug).
__global__ __launch_bounds__(256) void pv_kernel(const float* __restrict__ attn,
                                                 const f16* __restrict__ vt16,
                                                 f16* __restrict__ oh) {
    __shared__ f16 Pt[128][40];  // [q][k]
    __shared__ f16 Vt[64][40];   // [d][k]
    const int t = threadIdx.x;
    const int qt = 7 - (blockIdx.x >> 5);  // heavy first
    const int bh = blockIdx.x & 31;
    const int b = bh & 1, h = bh >> 1;
    const int q0 = qt << 7;
    const int wave = t >> 6, lane = t & 63;
    const int l16 = lane & 15, quad = lane >> 4;
    const int pr = t >> 1, pc = (t & 1) * 16;
    const int vd = t >> 2, vc = (t & 3) * 8;
    const float* Pg = attn + ((size_t)(b * 16 + h) << 20) + (size_t)(q0 + pr) * 1024 + pc;
    const f16* Vg = vt16 + (size_t)(bh * 64 + vd) * 1024 + vc;
    f32x4 acc[2][4] = {};
    const int nkt = (q0 >> 5) + 4;
    for (int kt = 0; kt < nkt; ++kt) {
        const int kbase = kt << 5;
        __syncthreads();
        {
            h2 o[8];
#pragma unroll
            for (int jj = 0; jj < 4; ++jj) {
                float4 v = *(const float4*)(Pg + kbase + jj * 4);
                o[jj * 2][0] = (f16)v.x;
                o[jj * 2][1] = (f16)v.y;
                o[jj * 2 + 1][0] = (f16)v.z;
                o[jj * 2 + 1][1] = (f16)v.w;
            }
            *(uint4*)&Pt[pr][pc] = *(uint4*)&o[0];
            *(uint4*)&Pt[pr][pc + 8] = *(uint4*)&o[4];
            *(uint4*)&Vt[vd][vc] = *(const uint4*)(Vg + kbase);
        }
        __syncthreads();
        f16x8 a[2], bf[4];
#pragma unroll
        for (int mi = 0; mi < 2; ++mi)
            a[mi] = *(const f16x8*)&Pt[wave * 32 + mi * 16 + l16][quad * 8];
#pragma unroll
        for (int ni = 0; ni < 4; ++ni)
            bf[ni] = *(const f16x8*)&Vt[ni * 16 + l16][quad * 8];
#pragma unroll
        for (int mi = 0; mi < 2; ++mi)
#pragma unroll
            for (int ni = 0; ni < 4; ++ni)
                acc[mi][ni] = mfma_f16(a[mi], bf[ni], acc[mi][ni]);
    }
#pragma unroll
    for (int mi = 0; mi < 2; ++mi)
#pragma unroll
        for (int ni = 0; ni < 4; ++ni)
#pragma unroll
            for (int rg = 0; rg < 4; ++rg) {
                int q = q0 + wave * 32 + mi * 16 + quad * 4 + rg;
                int d = ni * 16 + l16;
                oh[(size_t)(b * 1024 + q) * 1024 + h * 64 + d] = (f16)acc[mi][ni][rg];
            }
}

// ----------------------------------------------------------------
extern "C" void kernel_launch(void* const* d_in, const int* in_sizes, int n_in,
                              void* d_out, int out_size, void* d_ws, size_t ws_size,
                              hipStream_t stream) {
    const float* x  = (const float*)d_in[0];
    const float* Wq = (const float*)d_in[2];
    const float* bq = (const float*)d_in[3];
    const float* Wk = (const float*)d_in[4];
    const float* bk = (const float*)d_in[5];
    const float* Wv = (const float*)d_in[6];
    const float* bv = (const float*)d_in[7];
    const float* Wo = (const float*)d_in[8];
    const float* bo = (const float*)d_in[9];
    const float* Wg = (const float*)d_in[10];
    const float* bg = (const float*)d_in[11];
    const float* lt = (const float*)d_in[12];
    float* out = (float*)d_out;
    float* attn = out + (size_t)2 * 1024 * 1024;

    char* ws = (char*)d_ws;
    const size_t MB = (size_t)1 << 20;
    f16*   x16   = (f16*)ws;                  // 4 MiB (2048x1024)
    f16*   w16   = (f16*)(ws + 4 * MB);       // 6 MiB (Wq|Wk|Wv 3072x1024)
    f16*   wo16  = (f16*)(ws + 10 * MB);      // 2 MiB
    f16*   qkv16 = (f16*)(ws + 12 * MB);      // 12 MiB (2048x3072)
    f16*   vt16  = (f16*)(ws + 24 * MB);      // 4 MiB (V^T per head)
    float* gbuf  = (float*)(ws + 28 * MB);    // 128 KiB
    f16*   oh16  = (f16*)(ws + 29 * MB);      // 4 MiB — total 33 MiB

    cvt_kernel<<<2048, 256, 0, stream>>>(x, x16, 524288);
    cvt_kernel<<<1024, 256, 0, stream>>>(Wq, w16, 262144);
    cvt_kernel<<<1024, 256, 0, stream>>>(Wk, w16 + (1 << 20), 262144);
    cvt_kernel<<<1024, 256, 0, stream>>>(Wv, w16 + (2 << 20), 262144);
    cvt_kernel<<<1024, 256, 0, stream>>>(Wo, wo16, 262144);
    gate_kernel<<<2048, 256, 0, stream>>>(x, Wg, bg, gbuf);
    gemm128<true><<<dim3(48, 16), 256, 0, stream>>>(x16, w16, qkv16, bq, bk, bv,
                                                    1024, 1024, 1024, 3072);
    vtrans_kernel<<<512, 256, 0, stream>>>(qkv16, vt16);
    scores_kernel<<<2048, 256, 0, stream>>>(qkv16, gbuf, lt, attn);
    pv_kernel<<<256, 256, 0, stream>>>(attn, vt16, oh16);
    gemm128<false><<<dim3(16, 16), 256, 0, stream>>>(oh16, wo16, out, bo, bo, bo,
                                                     1024, 1024, 1024, 1024);
}

// Round 7
// 304.795 us; speedup vs baseline: 1.5238x; 1.1178x over previous
//
#include <hip/hip_runtime.h>

// TropicalMultiHeadAttention — MI355X (gfx950)  Round 7
// B=2, L=1024, D=1024, H=16, dk=64, SCALE=0.125; causal (mask input ignored).
// Outputs: out (2,1024,1024) f32 ++ attn (2,16,1024,1024) f32.
//
// R7 vs R6 (340us, scores 99us LDS-read-bound, 11 launches):
//  * scores: 2 keys/thread per Q-fragment load -> halves ds_read_b128 traffic
//    (LDS unit was the bottleneck: 4 waves x 96 LDS-cyc vs 192 VALU-cyc per q-iter)
//  * PV fused into scores (MFMA over normalized f16 P in LDS + L2-hot V^T) ->
//    pv_kernel + vtrans + 39MB attn re-fetch eliminated
//  * V^T produced in qkv-gemm epilogue (V column-tiles write transposed only)
//  * 5 cvt kernels merged into 1.  Pipeline: cvt, gate, gemm_qkv, scores_fused, gemm_out.

typedef _Float16 f16;
typedef __attribute__((ext_vector_type(2))) _Float16 h2;
typedef __attribute__((ext_vector_type(8))) _Float16 f16x8;
typedef __attribute__((ext_vector_type(4))) float f32x4;

__device__ inline f32x4 mfma_f16(f16x8 a, f16x8 b, f32x4 c) {
    return __builtin_amdgcn_mfma_f32_16x16x32_f16(a, b, c, 0, 0, 0);
}

__device__ inline void async_copy16(const f16* g, f16* l) {
    __builtin_amdgcn_global_load_lds((const __attribute__((address_space(1))) void*)g,
                                     (__attribute__((address_space(3))) void*)l, 16, 0, 0);
}

__device__ inline float dot2acc(h2 a, h2 b, float c) {
#if __has_builtin(__builtin_amdgcn_fdot2)
    return __builtin_amdgcn_fdot2(a, b, c, false);
#else
    c = fmaf((float)a[0], (float)b[0], c);
    return fmaf((float)a[1], (float)b[1], c);
#endif
}

// ---------------------------------------------------------------- all f32->f16 converts, one kernel
__global__ __launch_bounds__(256) void cvt_all(const float* __restrict__ x,
                                               const float* __restrict__ Wq,
                                               const float* __restrict__ Wk,
                                               const float* __restrict__ Wv,
                                               const float* __restrict__ Wo,
                                               f16* __restrict__ x16,
                                               f16* __restrict__ w16,
                                               f16* __restrict__ wo16) {
    int i = blockIdx.x * 256 + threadIdx.x;  // float4 index, 1572864 total
    const float* s;
    f16* d;
    int off;
    if (i < 524288)       { s = x;  d = x16;             off = i; }
    else if (i < 786432)  { s = Wq; d = w16;             off = i - 524288; }
    else if (i < 1048576) { s = Wk; d = w16 + (1 << 20); off = i - 786432; }
    else if (i < 1310720) { s = Wv; d = w16 + (2 << 20); off = i - 1048576; }
    else                  { s = Wo; d = wo16;            off = i - 1310720; }
    float4 v = *(const float4*)(s + (size_t)off * 4);
    f16 o[4] = {(f16)v.x, (f16)v.y, (f16)v.z, (f16)v.w};
    *(uint2*)(d + (size_t)off * 4) = *(uint2*)o;
}

// ---------------------------------------------------------------- gate: block = one row, 16 lanes/head
__global__ __launch_bounds__(256) void gate_kernel(const float* __restrict__ x,
                                                   const float* __restrict__ Wg,
                                                   const float* __restrict__ bg,
                                                   float* __restrict__ gbuf) {
    const int row = blockIdx.x;  // 0..2047
    const int t = threadIdx.x;
    const int h = t >> 4, li = t & 15;
    const float* xp = x + (size_t)row * 1024;
    const float* wp = Wg + (size_t)h * 1024;
    float acc = 0.f;
#pragma unroll
    for (int j = 0; j < 16; ++j) {
        int d = li * 4 + j * 64;
        float4 xv = *(const float4*)(xp + d);
        float4 wv = *(const float4*)(wp + d);
        acc = fmaf(xv.x, wv.x, acc);
        acc = fmaf(xv.y, wv.y, acc);
        acc = fmaf(xv.z, wv.z, acc);
        acc = fmaf(xv.w, wv.w, acc);
    }
#pragma unroll
    for (int o = 8; o > 0; o >>= 1) acc += __shfl_xor(acc, o);
    if (li == 0) gbuf[(size_t)row * 16 + h] = 1.0f / (1.0f + __expf(-(acc + bg[h])));
}

// ---------------------------------------------------------------- 128x64 MFMA GEMM  C = A @ B^T + bias
// Async global_load_lds staging (R6-proven). VTR: V column-tiles (n0>=2048) write V^T to vt
// at ((b*16+h)*64+d)*1024+k instead of C.
template <bool OUT16, bool VTR>
__global__ __launch_bounds__(256) void gemm128(const f16* __restrict__ A,
                                               const f16* __restrict__ B,
                                               void* __restrict__ Cv,
                                               const float* __restrict__ b0,
                                               const float* __restrict__ b1,
                                               const float* __restrict__ b2,
                                               f16* __restrict__ vt,
                                               int K, int lda, int ldb, int ldc) {
    __shared__ f16 At[128 * 32];
    __shared__ f16 Bt[64 * 32];
    const int t = threadIdx.x;
    const int m0 = blockIdx.y * 128, n0 = blockIdx.x * 64;
    const int wave = t >> 6, lane = t & 63;
    const int l16 = lane & 15, quad = lane >> 4;
    const int wm = (wave >> 1) * 64, wn = (wave & 1) * 32;
    const int sr = t >> 2, sc = (t & 3) * 8;
    f32x4 acc[4][2] = {};
    for (int k0 = 0; k0 < K; k0 += 32) {
        __syncthreads();
#pragma unroll
        for (int i = 0; i < 2; ++i)
            async_copy16(A + (size_t)(m0 + sr + i * 64) * lda + k0 + sc, &At[t * 8 + i * 2048]);
        async_copy16(B + (size_t)(n0 + sr) * ldb + k0 + sc, &Bt[t * 8]);
        __syncthreads();
        f16x8 af[4], bfr[2];
#pragma unroll
        for (int i = 0; i < 4; ++i)
            af[i] = *(const f16x8*)&At[(wm + i * 16 + l16) * 32 + quad * 8];
#pragma unroll
        for (int i = 0; i < 2; ++i)
            bfr[i] = *(const f16x8*)&Bt[(wn + i * 16 + l16) * 32 + quad * 8];
#pragma unroll
        for (int mi = 0; mi < 4; ++mi)
#pragma unroll
            for (int ni = 0; ni < 2; ++ni)
                acc[mi][ni] = mfma_f16(af[mi], bfr[ni], acc[mi][ni]);
    }
#pragma unroll
    for (int mi = 0; mi < 4; ++mi) {
#pragma unroll
        for (int ni = 0; ni < 2; ++ni) {
            int gcol = n0 + wn + ni * 16 + l16;
            const float* bp = (gcol < 1024) ? b0 : (gcol < 2048 ? b1 : b2);
            float bias = bp[gcol & 1023];
            if (VTR && n0 >= 2048) {
                // V tile: write transposed only. rows = k, cols = head-dim.
                int hd = gcol - 2048;
                int h = hd >> 6, d = hd & 63;
                int k0r = m0 + wm + mi * 16 + quad * 4;  // 4 consecutive k
                int b = k0r >> 10;
                f16 o4[4];
#pragma unroll
                for (int rg = 0; rg < 4; ++rg) o4[rg] = (f16)(acc[mi][ni][rg] + bias);
                *(uint2*)&vt[((size_t)((b * 16 + h) * 64 + d)) * 1024 + (k0r & 1023)] =
                    *(uint2*)o4;
            } else {
#pragma unroll
                for (int rg = 0; rg < 4; ++rg) {
                    int grow = m0 + wm + mi * 16 + quad * 4 + rg;
                    float v = acc[mi][ni][rg] + bias;
                    if (OUT16)
                        ((f16*)Cv)[(size_t)grow * ldc + gcol] = (f16)v;
                    else
                        ((float*)Cv)[(size_t)grow * ldc + gcol] = v;
                }
            }
        }
    }
}

// ---------------------------------------------------------------- scores + softmax + attn + PV (fused)
// Block: (b,h,16-row q-tile). Phase1: packed-f16 tropical+dot, 2 keys/thread per Q-frag load.
// Phase2: causal softmax; writes attn (f32) AND normalized P (f16) back into Ssm (zeros above diag).
// Phase3: O = P @ V via MFMA; A-frags from Ssm, B-frags from L2-hot vt16.
__global__ __launch_bounds__(256) void scores_fused(const f16* __restrict__ qkv16,
                                                    const f16* __restrict__ vt16,
                                                    const float* __restrict__ gbuf,
                                                    const float* __restrict__ log_temps,
                                                    float* __restrict__ attn,
                                                    f16* __restrict__ oh) {
    __shared__ f16 Qs[16][64];
    __shared__ f16 Ssm[16][1032];  // stride 1032: spreads PV a-frag rows across banks
    __shared__ float gsm[16];
    const int t = threadIdx.x;
    const int qt = 63 - (blockIdx.x >> 5);  // heavy tiles first
    const int bh = blockIdx.x & 31;
    const int b = bh & 1, h = bh >> 1;
    const int q0 = qt << 4;
    {
        int rr = t >> 4, cc = (t & 15) * 4;
        *(uint2*)&Qs[rr][cc] =
            *(const uint2*)(qkv16 + (size_t)(b * 1024 + q0 + rr) * 3072 + h * 64 + cc);
    }
    if (t < 16) gsm[t] = gbuf[(size_t)(b * 1024 + q0 + t) * 16 + h];
    float tau = __expf(log_temps[h]);
    tau = fminf(fmaxf(tau, 0.02f), 10.0f);
    const float invtau = 1.0f / tau;
    __syncthreads();

    const int qmax = q0 + 15;
    const int npass = (qmax >> 9) + 1;  // 512-key passes
    for (int p = 0; p < npass; ++p) {
        const int k1 = (p << 9) + t;
        const int k2 = k1 + 256;
        const bool a1 = (k1 <= qmax), a2 = (k2 <= qmax);
        if (a1) {
            const f16* Kp1 = qkv16 + (size_t)(b * 1024 + k1) * 3072 + 1024 + h * 64;
            h2 kr1[32], kr2[32];
#pragma unroll
            for (int i = 0; i < 8; ++i) *(f16x8*)&kr1[i * 4] = ((const f16x8*)Kp1)[i];
            if (a2) {
                const f16* Kp2 = qkv16 + (size_t)(b * 1024 + k2) * 3072 + 1024 + h * 64;
#pragma unroll
                for (int i = 0; i < 8; ++i) *(f16x8*)&kr2[i * 4] = ((const f16x8*)Kp2)[i];
            }
#pragma unroll 2
            for (int q = 0; q < 16; ++q) {
                h2 qr[32];
#pragma unroll
                for (int i = 0; i < 8; ++i) *(f16x8*)&qr[i * 4] = *(const f16x8*)&Qs[q][i * 8];
                float g = gsm[q];
                {
                    float dot = 0.f;
                    h2 tm2 = {(f16)-65504.f, (f16)-65504.f};
#pragma unroll
                    for (int i = 0; i < 32; ++i) {
                        h2 qa = qr[i];
                        h2 s2 = qa + kr1[i];
                        tm2 = __builtin_elementwise_max(tm2, s2);
                        dot = dot2acc(qa, kr1[i], dot);
                    }
                    float tm = fmaxf((float)tm2[0], (float)tm2[1]);
                    Ssm[q][k1] = (f16)((g * tm + (1.0f - g) * dot) * 0.125f);
                }
                if (a2) {
                    float dot = 0.f;
                    h2 tm2 = {(f16)-65504.f, (f16)-65504.f};
#pragma unroll
                    for (int i = 0; i < 32; ++i) {
                        h2 qa = qr[i];
                        h2 s2 = qa + kr2[i];
                        tm2 = __builtin_elementwise_max(tm2, s2);
                        dot = dot2acc(qa, kr2[i], dot);
                    }
                    float tm = fmaxf((float)tm2[0], (float)tm2[1]);
                    Ssm[q][k2] = (f16)((g * tm + (1.0f - g) * dot) * 0.125f);
                }
            }
        }
    }
    __syncthreads();

    const int lane = t & 63, w = t >> 6;
    const int l16 = lane & 15, quad = lane >> 4;
#pragma unroll
    for (int j = 0; j < 4; ++j) {
        int q = w * 4 + j;
        int qg = q0 + q;
        float m = -1e30f;
        for (int k = lane; k <= qg; k += 64) m = fmaxf(m, (float)Ssm[q][k]);
#pragma unroll
        for (int o = 32; o > 0; o >>= 1) m = fmaxf(m, __shfl_xor(m, o));
        float ssum = 0.f;
        for (int k = lane; k <= qg; k += 64) {
            float e = __expf(((float)Ssm[q][k] - m) * invtau);
            Ssm[q][k] = (f16)e;
            ssum += e;
        }
#pragma unroll
        for (int o = 32; o > 0; o >>= 1) ssum += __shfl_xor(ssum, o);
        float inv = 1.0f / ssum;
        float* orow = attn + ((size_t)((b * 16 + h) * 1024 + qg) << 10);
        for (int k = lane; k < 1024; k += 64) {
            float val = (k <= qg) ? (float)Ssm[q][k] * inv : 0.0f;
            orow[k] = val;
            Ssm[q][k] = (f16)val;  // normalized P (zeros above diag) for PV
        }
    }
    __syncthreads();

    // Phase 3: O(16x64) = P(16x1024) @ V(1024x64); wave w owns d-tile [w*16, w*16+16)
    {
        const int dw = w * 16;
        f32x4 acc = {};
        const int nkt = (q0 + 47) >> 5;  // ceil((qmax+1)/32)
        const f16* Vb = vt16 + ((size_t)((b * 16 + h) * 64 + dw + l16)) * 1024 + quad * 8;
#pragma unroll 4
        for (int kt = 0; kt < nkt; ++kt) {
            const int kb = kt << 5;
            f16x8 a = *(const f16x8*)&Ssm[l16][kb + quad * 8];
            f16x8 bf = *(const f16x8*)(Vb + kb);
            acc = mfma_f16(a, bf, acc);
        }
#pragma unroll
        for (int rg = 0; rg < 4; ++rg)
            oh[(size_t)(b * 1024 + q0 + quad * 4 + rg) * 1024 + h * 64 + dw + l16] =
                (f16)acc[rg];
    }
}

// ----------------------------------------------------------------
extern "C" void kernel_launch(void* const* d_in, const int* in_sizes, int n_in,
                              void* d_out, int out_size, void* d_ws, size_t ws_size,
                              hipStream_t stream) {
    const float* x  = (const float*)d_in[0];
    const float* Wq = (const float*)d_in[2];
    const float* bq = (const float*)d_in[3];
    const float* Wk = (const float*)d_in[4];
    const float* bk = (const float*)d_in[5];
    const float* Wv = (const float*)d_in[6];
    const float* bv = (const float*)d_in[7];
    const float* Wo = (const float*)d_in[8];
    const float* bo = (const float*)d_in[9];
    const float* Wg = (const float*)d_in[10];
    const float* bg = (const float*)d_in[11];
    const float* lt = (const float*)d_in[12];
    float* out = (float*)d_out;
    float* attn = out + (size_t)2 * 1024 * 1024;

    char* ws = (char*)d_ws;
    const size_t MB = (size_t)1 << 20;
    f16*   x16   = (f16*)ws;                  // 4 MiB (2048x1024)
    f16*   w16   = (f16*)(ws + 4 * MB);       // 6 MiB (Wq|Wk|Wv 3072x1024)
    f16*   wo16  = (f16*)(ws + 10 * MB);      // 2 MiB
    f16*   qkv16 = (f16*)(ws + 12 * MB);      // 12 MiB (Q,K used; V third unused)
    f16*   vt16  = (f16*)(ws + 24 * MB);      // 4 MiB (V^T per (b*16+h))
    float* gbuf  = (float*)(ws + 28 * MB);    // 128 KiB
    f16*   oh16  = (f16*)(ws + 29 * MB);      // 4 MiB — total 33 MiB

    cvt_all<<<6144, 256, 0, stream>>>(x, Wq, Wk, Wv, Wo, x16, w16, wo16);
    gate_kernel<<<2048, 256, 0, stream>>>(x, Wg, bg, gbuf);
    gemm128<true, true><<<dim3(48, 16), 256, 0, stream>>>(x16, w16, qkv16, bq, bk, bv,
                                                          vt16, 1024, 1024, 1024, 3072);
    scores_fused<<<2048, 256, 0, stream>>>(qkv16, vt16, gbuf, lt, attn, oh16);
    gemm128<false, false><<<dim3(16, 16), 256, 0, stream>>>(oh16, wo16, out, bo, bo, bo,
                                                            nullptr, 1024, 1024, 1024, 1024);
}